// Round 3
// baseline (377.514 us; speedup 1.0000x reference)
//
#include <hip/hip_runtime.h>

// Problem constants (fixed by the reference file).
#define N_NODES 8192
#define DIM     256
#define NH      64
#define DEG     32
#define G       4      // nodes per block in QKV kernel
// G tradeoff: weight L2 traffic = (N/G)*192KB, wave count = N/G.
// G=8 -> 1 wave/SIMD (latency exposed); G=4 -> 2 waves/SIMD, 384MB L2 (~11us).

// Kernel A: QKV projection, G nodes per 64-thread block.
// Thread t owns output dim t for all G nodes and all 3 matrices.
// x-rows staged in LDS (f32, broadcast reads); W rows streamed as float4 from L2.
__global__ __launch_bounds__(64) void qkv_kernel(
    const float* __restrict__ x,
    const float* __restrict__ Wq, const float* __restrict__ bq,
    const float* __restrict__ Wk, const float* __restrict__ bk,
    const float* __restrict__ Wv,
    float* __restrict__ Q, float* __restrict__ K, float* __restrict__ V)
{
    const int g0 = blockIdx.x * G;      // first node of this block
    const int t  = threadIdx.x;         // 0..63 = output dim

    __shared__ float xs[G * DIM];       // 4 KB

    // Stage G x-rows: G*DIM = 1024 floats = 256 float4; 4 per thread, coalesced.
    const float4* xin = (const float4*)(x + (size_t)g0 * DIM);
    float4* xs4 = (float4*)xs;
    #pragma unroll
    for (int c = 0; c < (G * DIM / 4) / 64; ++c)
        xs4[t + 64 * c] = xin[t + 64 * c];
    __syncthreads();

    const float4* wq = (const float4*)(Wq + t * DIM);
    const float4* wk = (const float4*)(Wk + t * DIM);
    const float4* wv = (const float4*)(Wv + t * DIM);

    float accq[G], acck[G], accv[G];
    #pragma unroll
    for (int m = 0; m < G; ++m) { accq[m] = 0.f; acck[m] = 0.f; accv[m] = 0.f; }

    #pragma unroll 4
    for (int c = 0; c < DIM / 4; ++c) {         // 64 iterations
        const float4 aq = wq[c];
        const float4 ak = wk[c];
        const float4 av = wv[c];
        #pragma unroll
        for (int m = 0; m < G; ++m) {
            // wave-uniform address -> LDS broadcast, no bank conflicts
            const float4 xv = ((const float4*)(xs + m * DIM))[c];
            accq[m] += xv.x * aq.x + xv.y * aq.y + xv.z * aq.z + xv.w * aq.w;
            acck[m] += xv.x * ak.x + xv.y * ak.y + xv.z * ak.z + xv.w * ak.w;
            accv[m] += xv.x * av.x + xv.y * av.y + xv.z * av.z + xv.w * av.w;
        }
    }

    const float bqv = bq[t];
    const float bkv = bk[t];
    #pragma unroll
    for (int m = 0; m < G; ++m) {
        const int o = (g0 + m) * NH + t;        // coalesced per m
        Q[o] = accq[m] + bqv;
        K[o] = acck[m] + bkv;
        V[o] = accv[m];
    }
}

// Kernel B: sparse attention over the 32 neighbors of each node.
// One wave per node. Lanes 0..31: score for neighbor j = (Q_i . K_j + ek)/512
// (the reference's /H then /sqrt(H), H=64). 64-lane shuffle softmax
// (inactive lanes carry -1e30 -> exp == 0). Neighbor ids and probabilities
// broadcast lane->wave via __shfl (no LDS, no extra barriers). Then all 64
// lanes accumulate O[i][t] = sum_j p_j * V[nbr_j][t] (coalesced 256B/neighbor).
__global__ __launch_bounds__(64) void attn_kernel(
    const float* __restrict__ Q, const float* __restrict__ K,
    const float* __restrict__ V,
    const int* __restrict__ edge_dst,     // [E]; node i owns e = i*DEG .. +DEG-1
    const int* __restrict__ edge_type,    // [E]
    const float* __restrict__ ektab,      // [NTYPES]
    float* __restrict__ out)              // [N, NH] f32
{
    const int i = blockIdx.x;
    const int t = threadIdx.x;            // 0..63

    __shared__ float qs[NH];
    qs[t] = Q[i * NH + t];
    __syncthreads();                      // single-wave block: cheap

    float s = -1e30f;
    int nbr = 0;
    if (t < DEG) {
        const int e = i * DEG + t;
        nbr = edge_dst[e];
        const float ek = ektab[edge_type[e]];
        const float4* kr = (const float4*)(K + (size_t)nbr * NH);
        const float4* q4 = (const float4*)qs;
        float acc = 0.f;
        #pragma unroll
        for (int d = 0; d < NH / 4; ++d) {
            const float4 kv = kr[d];
            const float4 qv = q4[d];      // uniform address -> broadcast
            acc += qv.x * kv.x + qv.y * kv.y + qv.z * kv.z + qv.w * kv.w;
        }
        s = (acc + ek) * (1.0f / 512.0f);   // /H then /sqrt(H): 64*8
    }

    // wave softmax across 64 lanes (lanes >= DEG contribute exp -> 0)
    float m = s;
    #pragma unroll
    for (int off = 32; off > 0; off >>= 1) m = fmaxf(m, __shfl_xor(m, off));
    float p = __expf(s - m);
    float l = p;
    #pragma unroll
    for (int off = 32; off > 0; off >>= 1) l += __shfl_xor(l, off);
    p /= l;

    float o = 0.f;
    #pragma unroll 8
    for (int j = 0; j < DEG; ++j) {
        const float pj = __shfl(p, j);          // lane j holds neighbor j's prob
        const int   nj = __shfl(nbr, j);
        o += pj * V[(size_t)nj * NH + t];
    }

    out[i * NH + t] = o;
}

extern "C" void kernel_launch(void* const* d_in, const int* in_sizes, int n_in,
                              void* d_out, int out_size, void* d_ws, size_t ws_size,
                              hipStream_t stream) {
    // setup_inputs order (all floats f32 per the reference):
    // 0:x [N,D]  1:adj [N,N] (UNUSED)  2:edge_index [2,E] i32
    // 3:edge_type [E] i32  4:Wq [H,D]  5:bq [H]  6:Wk  7:bk  8:Wv
    // 9:edge_k_table [16,1]
    const float* x     = (const float*)d_in[0];
    const int*   eidx  = (const int*)d_in[2];
    const int*   etyp  = (const int*)d_in[3];
    const float* Wq    = (const float*)d_in[4];
    const float* bq    = (const float*)d_in[5];
    const float* Wk    = (const float*)d_in[6];
    const float* bk    = (const float*)d_in[7];
    const float* Wv    = (const float*)d_in[8];
    const float* ektab = (const float*)d_in[9];
    float*       out   = (float*)d_out;

    const int E = in_sizes[2] / 2;        // 262144

    float* Q = (float*)d_ws;              // [N, NH] f32
    float* K = Q + (size_t)N_NODES * NH;
    float* V = K + (size_t)N_NODES * NH;  // 6 MB of ws

    qkv_kernel<<<dim3(N_NODES / G), dim3(64), 0, stream>>>(x, Wq, bq, Wk, bk, Wv, Q, K, V);
    attn_kernel<<<dim3(N_NODES), dim3(64), 0, stream>>>(Q, K, V, eidx + E, etyp, ektab, out);
}

// Round 5
// 357.696 us; speedup vs baseline: 1.0554x; 1.0554x over previous
//
#include <hip/hip_runtime.h>

// Problem constants (fixed by the reference file).
#define N_NODES 8192
#define DIM     256
#define NH      64
#define DEG     32
#define G       8      // nodes per QKV block (8 nodes, 2 waves, split-K)
// Kernel A design: weight L2 traffic = (N/G)*192KB = 192 MB (~5.6 us at L2
// 34.5 TB/s) while 2 waves/block keep 2 waves/SIMD for latency hiding.
// VALU floor: 805 MFLOP f32 / 157 TF ~= 5.1 us -> A is balanced at ~6-7 us.

// Kernel A: QKV projection, G=8 nodes per 128-thread (2-wave) block, split-K.
// Wave w covers reduction half [w*128, w*128+128) of DIM. Lane t owns output
// dim t. Cross-wave partials go through LDS indexed by ABSOLUTE node slot
// (wave w writes slots of the other wave's nodes; disjoint, no race —
// round 4's bug was both waves writing the same slots).
__global__ __launch_bounds__(128) void qkv_kernel(
    const float* __restrict__ x,
    const float* __restrict__ Wq, const float* __restrict__ bq,
    const float* __restrict__ Wk, const float* __restrict__ bk,
    const float* __restrict__ Wv,
    float* __restrict__ Q, float* __restrict__ K, float* __restrict__ V)
{
    const int g0 = blockIdx.x * G;        // first node of this block
    const int t  = threadIdx.x & 63;      // 0..63 = output dim
    const int w  = threadIdx.x >> 6;      // wave id: 0 or 1

    __shared__ float xs[G * DIM];         // 8 KB: 8 x-rows
    __shared__ float red[3][G][64];       // 6 KB: cross-wave partials by node slot

    // Stage 8 x-rows: 2048 floats = 512 float4; 4 per thread, coalesced.
    const float4* xin = (const float4*)(x + (size_t)g0 * DIM);
    float4* xs4 = (float4*)xs;
    #pragma unroll
    for (int c = 0; c < (G * DIM / 4) / 128; ++c)
        xs4[threadIdx.x + 128 * c] = xin[threadIdx.x + 128 * c];
    __syncthreads();

    const int c0 = w * (DIM / 4 / 2);     // this wave's half of K-dim (float4 idx)
    const float4* wq = (const float4*)(Wq + t * DIM) + c0;
    const float4* wk = (const float4*)(Wk + t * DIM) + c0;
    const float4* wv = (const float4*)(Wv + t * DIM) + c0;

    float accq[G], acck[G], accv[G];
    #pragma unroll
    for (int m = 0; m < G; ++m) { accq[m] = 0.f; acck[m] = 0.f; accv[m] = 0.f; }

    #pragma unroll 4
    for (int c = 0; c < DIM / 4 / 2; ++c) {       // 32 iterations per wave
        const float4 aq = wq[c];
        const float4 ak = wk[c];
        const float4 av = wv[c];
        #pragma unroll
        for (int m = 0; m < G; ++m) {
            // wave-uniform address -> LDS broadcast, no bank conflicts
            const float4 xv = ((const float4*)(xs + m * DIM))[c0 + c];
            accq[m] += xv.x * aq.x + xv.y * aq.y + xv.z * aq.z + xv.w * aq.w;
            acck[m] += xv.x * ak.x + xv.y * ak.y + xv.z * ak.z + xv.w * ak.w;
            accv[m] += xv.x * av.x + xv.y * av.y + xv.z * av.z + xv.w * av.w;
        }
    }

    // Publish partials for the OTHER wave's nodes, indexed by absolute slot:
    // wave 0 writes slots 4..7, wave 1 writes slots 0..3 -> disjoint.
    const int other0 = (1 - w) * (G / 2);
    #pragma unroll
    for (int m = 0; m < G / 2; ++m) {
        red[0][other0 + m][t] = accq[other0 + m];
        red[1][other0 + m][t] = acck[other0 + m];
        red[2][other0 + m][t] = accv[other0 + m];
    }
    __syncthreads();

    const float bqv = bq[t];
    const float bkv = bk[t];
    const int mine0 = w * (G / 2);        // wave w stores nodes [w*4, w*4+4)
    #pragma unroll
    for (int m = 0; m < G / 2; ++m) {
        const int slot = mine0 + m;
        const int o = (g0 + slot) * NH + t;       // coalesced per m
        Q[o] = accq[slot] + red[0][slot][t] + bqv;
        K[o] = acck[slot] + red[1][slot][t] + bkv;
        V[o] = accv[slot] + red[2][slot][t];
    }
}

// Kernel B: sparse attention over the 32 neighbors of each node.
// One wave per node. Lanes 0..31: score for neighbor j = (Q_i . K_j + ek)/512
// (the reference's /H then /sqrt(H), H=64). 64-lane shuffle softmax
// (inactive lanes carry -1e30 -> exp == 0). Neighbor ids and probabilities
// broadcast lane->wave via __shfl. Then all 64 lanes accumulate
// O[i][t] = sum_j p_j * V[nbr_j][t] (coalesced 256B per neighbor).
__global__ __launch_bounds__(64) void attn_kernel(
    const float* __restrict__ Q, const float* __restrict__ K,
    const float* __restrict__ V,
    const int* __restrict__ edge_dst,     // [E]; node i owns e = i*DEG .. +DEG-1
    const int* __restrict__ edge_type,    // [E]
    const float* __restrict__ ektab,      // [NTYPES]
    float* __restrict__ out)              // [N, NH] f32
{
    const int i = blockIdx.x;
    const int t = threadIdx.x;            // 0..63

    __shared__ float qs[NH];
    qs[t] = Q[i * NH + t];
    __syncthreads();                      // single-wave block: cheap

    float s = -1e30f;
    int nbr = 0;
    if (t < DEG) {
        const int e = i * DEG + t;
        nbr = edge_dst[e];
        const float ek = ektab[edge_type[e]];
        const float4* kr = (const float4*)(K + (size_t)nbr * NH);
        const float4* q4 = (const float4*)qs;
        float acc = 0.f;
        #pragma unroll
        for (int d = 0; d < NH / 4; ++d) {
            const float4 kv = kr[d];
            const float4 qv = q4[d];      // uniform address -> broadcast
            acc += qv.x * kv.x + qv.y * kv.y + qv.z * kv.z + qv.w * kv.w;
        }
        s = (acc + ek) * (1.0f / 512.0f);   // /H then /sqrt(H): 64*8
    }

    // wave softmax across 64 lanes (lanes >= DEG contribute exp -> 0)
    float m = s;
    #pragma unroll
    for (int off = 32; off > 0; off >>= 1) m = fmaxf(m, __shfl_xor(m, off));
    float p = __expf(s - m);
    float l = p;
    #pragma unroll
    for (int off = 32; off > 0; off >>= 1) l += __shfl_xor(l, off);
    p /= l;

    float o = 0.f;
    #pragma unroll 8
    for (int j = 0; j < DEG; ++j) {
        const float pj = __shfl(p, j);          // lane j holds neighbor j's prob
        const int   nj = __shfl(nbr, j);
        o += pj * V[(size_t)nj * NH + t];
    }

    out[i * NH + t] = o;
}

extern "C" void kernel_launch(void* const* d_in, const int* in_sizes, int n_in,
                              void* d_out, int out_size, void* d_ws, size_t ws_size,
                              hipStream_t stream) {
    // setup_inputs order (all floats f32 per the reference):
    // 0:x [N,D]  1:adj [N,N] (UNUSED)  2:edge_index [2,E] i32
    // 3:edge_type [E] i32  4:Wq [H,D]  5:bq [H]  6:Wk  7:bk  8:Wv
    // 9:edge_k_table [16,1]
    const float* x     = (const float*)d_in[0];
    const int*   eidx  = (const int*)d_in[2];
    const int*   etyp  = (const int*)d_in[3];
    const float* Wq    = (const float*)d_in[4];
    const float* bq    = (const float*)d_in[5];
    const float* Wk    = (const float*)d_in[6];
    const float* bk    = (const float*)d_in[7];
    const float* Wv    = (const float*)d_in[8];
    const float* ektab = (const float*)d_in[9];
    float*       out   = (float*)d_out;

    const int E = in_sizes[2] / 2;        // 262144

    float* Q = (float*)d_ws;              // [N, NH] f32
    float* K = Q + (size_t)N_NODES * NH;
    float* V = K + (size_t)N_NODES * NH;  // 6 MB of ws

    qkv_kernel<<<dim3(N_NODES / G), dim3(128), 0, stream>>>(x, Wq, bq, Wk, bk, Wv, Q, K, V);
    attn_kernel<<<dim3(N_NODES), dim3(64), 0, stream>>>(Q, K, V, eidx + E, etyp, ektab, out);
}